// Round 11
// baseline (109.752 us; speedup 1.0000x reference)
//
#include <hip/hip_runtime.h>
#include <hip/hip_bf16.h>
#include <stdint.h>
#include <stddef.h>

// NT-Xent loss, B=4096, D=256, N=8192, T=0.5.
// normalize(+zero sumexp) -> fused symmetric ZZ^T GEMM + exp row/col-sum +
// positive capture -> 1-block finalize/mean. No NxN materialization.
//
// R11: INTRA-WAVE PIPELINE. R1-R10 post-mortems: per-CU serial pipe demands
// (LDS ~10us + TA ~8us + VALU ~7us + MFMA ~8us) sum to the observed ~47us ->
// pipes never overlap because same-length phases convoy at each vmcnt wait
// (R10's VGPR=52 shows zero prefetch distance). Fix: each wave overlaps its
// OWN memory with its OWN MFMAs -- half-iteration register pipeline: B-group
// g+1 (4kq x 2 frags, 32 regs) loads in flight while group g computes
// (~620 cyc of MFMA >> 200-400 cyc L2 latency). launch_bounds(256,3): ~140
// regs fits 3 waves/SIMD without the forced-spill failure of (256,4)@R2.
// Carry-overs: R10 A-tile in LDS staged once (single barrier, XOR-swizzled,
// conflict-free), symmetry at 64-granularity, __builtin_amdgcn_exp2f.
// Harness note: ~58-60 us of dur_us is fixed overhead (268 MB ws re-poison
// fill + input restores) outside kernel control.

#define B_ROWS 4096
#define D_DIM  256
#define N_ROWS 8192
#define BM 64

typedef __bf16 bf16;
typedef bf16  bf16x8  __attribute__((ext_vector_type(8)));
typedef bf16  bf16x4  __attribute__((ext_vector_type(4)));
typedef float floatx4 __attribute__((ext_vector_type(4)));

// ---------------------------------------------------------------- normalize
// One wave per row: 256 fp32 -> L2-normalized bf16. Also zeroes sumexp[row].
__global__ __launch_bounds__(256) void normalize_kernel(
    const float* __restrict__ z_i, const float* __restrict__ z_j,
    bf16* __restrict__ zn, float* __restrict__ sumexp) {
  const int wave = threadIdx.x >> 6;
  const int lane = threadIdx.x & 63;
  const int row  = blockIdx.x * 4 + wave;
  const float* src = (row < B_ROWS) ? (z_i + (size_t)row * D_DIM)
                                    : (z_j + (size_t)(row - B_ROWS) * D_DIM);
  float4 v = ((const float4*)src)[lane];
  float ss = v.x * v.x + v.y * v.y + v.z * v.z + v.w * v.w;
  #pragma unroll
  for (int m = 1; m < 64; m <<= 1) ss += __shfl_xor(ss, m);
  const float rn = rsqrtf(ss);
  bf16x4 o;
  o[0] = (bf16)(v.x * rn);
  o[1] = (bf16)(v.y * rn);
  o[2] = (bf16)(v.z * rn);
  o[3] = (bf16)(v.w * rn);
  ((bf16x4*)(zn + (size_t)row * D_DIM))[lane] = o;
  if (lane == 0) sumexp[row] = 0.f;
}

// ------------------------------------------------------- fused sim+exp+sum
// Grid: 128 ri x 8 cj = 1024 blocks. Block (ri,cj): pairs s=8cj+p, p=0..7,
// two pairs per iteration (4 iters x 128 cols); cj==7,ri<64 also handles
// s=64 (positive tiles) as a 5th iteration on waves 0,1. 4 waves: wave w
// covers 64 rows x 32 cols of pair (w>>1), col slice (w&1)*32. acc[4][2]
// frags of 16x16x32 bf16 MFMA, full-D. A from LDS (XOR-swizzled slot
// (kc&24)|((kc&7)^(n&7)) -> quarter-wave 2-way = conflict-free). B from
// global/L2 through a 2-deep half-iteration register pipeline (bp->bc).
__global__ __launch_bounds__(256, 3) void simexp_kernel(
    const bf16* __restrict__ zn, float* __restrict__ sumexp,
    float* __restrict__ pos) {
  __shared__ __align__(16) bf16 As[BM * D_DIM];  // 32 KB

  const int tid   = threadIdx.x;
  const int wave  = tid >> 6;
  const int lane  = tid & 63;
  const int lcol  = lane & 15;   // MFMA: A/B input row-col index
  const int lquad = lane >> 4;   // MFMA: k-group / C row-group
  const int ri = blockIdx.x >> 3;   // row tile 0..127 (64-row granularity)
  const int cj = blockIdx.x & 7;    // s-chunk 0..7
  const int row_base = ri * BM;
  const bool tail_block = (cj == 7 && ri < 64);
  const int niter = tail_block ? 5 : 4;

  // stage A-tile once (8 x global_load_lds width-16 per thread)
  {
    const bf16* asrc = zn + (size_t)row_base * D_DIM;
    #pragma unroll
    for (int it = 0; it < 8; ++it) {
      const int s   = it * 256 + tid;   // chunk slot 0..2047
      const int n   = s >> 5;           // row-in-tile 0..63
      const int kcs = s & 31;           // swizzled slot
      const int kc  = (kcs & 24) | ((kcs & 7) ^ (n & 7));
      __builtin_amdgcn_global_load_lds(
          (const __attribute__((address_space(1))) unsigned int*)
              (asrc + (size_t)n * D_DIM + kc * 8),
          (__attribute__((address_space(3))) unsigned int*)&As[s * 8],
          16, 0, 0);
    }
  }

  // col tile for iteration q (wave-pair dependent)
  auto ctof = [&](int q) {
    return (q == 4) ? (ri + 64) : ((ri + 8 * cj + 2 * q + (wave >> 1)) & 127);
  };

  float rowsum[4][4];  // [ti][r]; row-in-tile = ti*16 + lquad*4 + r
  #pragma unroll
  for (int ti = 0; ti < 4; ++ti)
    #pragma unroll
    for (int r = 0; r < 4; ++r) rowsum[ti][r] = 0.f;

  // per-lane B element offsets within a 64-col tile (constant across iters)
  const int slice_col = (wave & 1) * 32;
  const int boff0 = (slice_col + lcol) * D_DIM + lquad * 8;        // tj=0
  const int boff1 = (slice_col + 16 + lcol) * D_DIM + lquad * 8;   // tj=1

  // prefetch pipeline: bp holds the NEXT half-iteration's 8 B-fragments
  bf16x8 bp[8];
  {
    const bf16* bb = zn + (size_t)ctof(0) * BM * D_DIM;
    #pragma unroll
    for (int k = 0; k < 4; ++k) {
      bp[2 * k]     = *(const bf16x8*)(bb + boff0 + k * 32);
      bp[2 * k + 1] = *(const bf16x8*)(bb + boff1 + k * 32);
    }
  }

  __syncthreads();  // the ONLY barrier: A staged & visible

  #pragma unroll 1
  for (int q = 0; q < niter; ++q) {
    const bool tail = (q == 4);
    if (tail && wave >= 2) break;  // tail pair served by waves 0,1 only
    const int ct = ctof(q);
    const bf16* bbase = zn + (size_t)ct * BM * D_DIM;

    floatx4 acc[4][2];
    #pragma unroll
    for (int ti = 0; ti < 4; ++ti)
      #pragma unroll
      for (int tj = 0; tj < 2; ++tj) acc[ti][tj] = floatx4{0.f, 0.f, 0.f, 0.f};

    // ---- half 1: consume bp (kq 0..3); issue loads for kq 4..7
    bf16x8 bc[8];
    #pragma unroll
    for (int i = 0; i < 8; ++i) bc[i] = bp[i];
    #pragma unroll
    for (int k = 0; k < 4; ++k) {
      bp[2 * k]     = *(const bf16x8*)(bbase + boff0 + (k + 4) * 32);
      bp[2 * k + 1] = *(const bf16x8*)(bbase + boff1 + (k + 4) * 32);
    }
    #pragma unroll
    for (int kq = 0; kq < 4; ++kq) {
      const int kc   = kq * 4 + lquad;
      const int slot = (kc & 24) | ((kc & 7) ^ (lcol & 7));
      #pragma unroll
      for (int ti = 0; ti < 4; ++ti) {
        const bf16x8 a =
            *(const bf16x8*)&As[(ti * 16 + lcol) * D_DIM + slot * 8];
        acc[ti][0] = __builtin_amdgcn_mfma_f32_16x16x32_bf16(
            a, bc[2 * kq], acc[ti][0], 0, 0, 0);
        acc[ti][1] = __builtin_amdgcn_mfma_f32_16x16x32_bf16(
            a, bc[2 * kq + 1], acc[ti][1], 0, 0, 0);
      }
    }

    // ---- half 2: consume bp (kq 4..7); issue loads for next iter's kq 0..3
    #pragma unroll
    for (int i = 0; i < 8; ++i) bc[i] = bp[i];
    if (q + 1 < niter) {
      const bf16* bb2 = zn + (size_t)ctof(q + 1) * BM * D_DIM;
      #pragma unroll
      for (int k = 0; k < 4; ++k) {
        bp[2 * k]     = *(const bf16x8*)(bb2 + boff0 + k * 32);
        bp[2 * k + 1] = *(const bf16x8*)(bb2 + boff1 + k * 32);
      }
    }
    #pragma unroll
    for (int kq = 4; kq < 8; ++kq) {
      const int kc   = kq * 4 + lquad;
      const int slot = (kc & 24) | ((kc & 7) ^ (lcol & 7));
      #pragma unroll
      for (int ti = 0; ti < 4; ++ti) {
        const bf16x8 a =
            *(const bf16x8*)&As[(ti * 16 + lcol) * D_DIM + slot * 8];
        acc[ti][0] = __builtin_amdgcn_mfma_f32_16x16x32_bf16(
            a, bc[2 * (kq - 4)], acc[ti][0], 0, 0, 0);
        acc[ti][1] = __builtin_amdgcn_mfma_f32_16x16x32_bf16(
            a, bc[2 * (kq - 4) + 1], acc[ti][1], 0, 0, 0);
      }
    }

    // epilogue: e = exp(sim/T) = exp(2*dot) = 2^(v * 2/ln2)
    const bool diagw = (cj == 0 && q == 0 && wave < 2);  // ct == ri tile
    const int col_base = ct * BM + slice_col;
    float colsum[2] = {0.f, 0.f};
    #pragma unroll
    for (int ti = 0; ti < 4; ++ti) {
      #pragma unroll
      for (int tj = 0; tj < 2; ++tj) {
        #pragma unroll
        for (int r = 0; r < 4; ++r) {
          const float v = acc[ti][tj][r];
          float e = __builtin_amdgcn_exp2f(v * 2.8853900817779268f);
          if (diagw || tail) {
            const int rg = row_base + ti * 16 + lquad * 4 + r;
            const int cg = col_base + tj * 16 + lcol;
            if (diagw && cg == rg) e = 0.f;              // mask self
            if (tail && cg == rg + B_ROWS) {             // positive pair
              pos[rg] = 2.0f * v;
              pos[cg] = 2.0f * v;
            }
          }
          rowsum[ti][r] += e;
          colsum[tj]    += e;
        }
      }
    }

    // symmetric contribution: col-sums -> rows(ct). Skip on the self-diag
    // tile (its row-sums already cover both orientations).
    if (!diagw) {
      #pragma unroll
      for (int tj = 0; tj < 2; ++tj) {
        float cs = colsum[tj];
        cs += __shfl_xor(cs, 16);
        cs += __shfl_xor(cs, 32);
        if (lquad == 0)
          atomicAdd(&sumexp[col_base + tj * 16 + lcol], cs);
      }
    }
  }

  // reduce the 16 col-lanes of rowsum, then 1 atomic per row per wave
  #pragma unroll
  for (int ti = 0; ti < 4; ++ti) {
    #pragma unroll
    for (int r = 0; r < 4; ++r) {
      float s2 = rowsum[ti][r];
      s2 += __shfl_xor(s2, 1);
      s2 += __shfl_xor(s2, 2);
      s2 += __shfl_xor(s2, 4);
      s2 += __shfl_xor(s2, 8);
      if (lcol == 0) {
        const int grow = row_base + ti * 16 + lquad * 4 + r;
        atomicAdd(&sumexp[grow], s2);
      }
    }
  }
}

// ------------------------------------------------- finalize + mean (1 block)
// loss_i = log(sumexp_i) - pos_i ; out = mean(loss)
__global__ __launch_bounds__(1024) void reduce_kernel(
    const float* __restrict__ sumexp, const float* __restrict__ pos,
    float* __restrict__ out) {
  __shared__ float ws[16];
  const int tid = threadIdx.x;
  float s = 0.f;
  const float ln2 = 0.6931471805599453f;
  for (int k = tid; k < N_ROWS; k += 1024)
    s += __builtin_amdgcn_logf(sumexp[k]) * ln2 - pos[k];
  #pragma unroll
  for (int m = 1; m < 64; m <<= 1) s += __shfl_xor(s, m);
  const int wave = tid >> 6, lane = tid & 63;
  if (lane == 0) ws[wave] = s;
  __syncthreads();
  if (wave == 0) {
    float t = (lane < 16) ? ws[lane] : 0.f;
    #pragma unroll
    for (int m = 1; m < 16; m <<= 1) t += __shfl_xor(t, m);
    if (lane == 0) out[0] = t * (1.0f / N_ROWS);
  }
}

extern "C" void kernel_launch(void* const* d_in, const int* in_sizes, int n_in,
                              void* d_out, int out_size, void* d_ws,
                              size_t ws_size, hipStream_t stream) {
  const float* z_i = (const float*)d_in[0];
  const float* z_j = (const float*)d_in[1];
  float* out = (float*)d_out;

  // workspace layout: zn (4 MB bf16) | sumexp (32 KB) | pos (32 KB)
  bf16* zn = (bf16*)d_ws;
  float* sumexp = (float*)((char*)d_ws + (size_t)N_ROWS * D_DIM * sizeof(bf16));
  float* pos = sumexp + N_ROWS;

  normalize_kernel<<<N_ROWS / 4, 256, 0, stream>>>(z_i, z_j, zn, sumexp);
  simexp_kernel<<<1024, 256, 0, stream>>>(zn, sumexp, pos);
  reduce_kernel<<<1, 1024, 0, stream>>>(sumexp, pos, out);
}

// Round 12
// 108.722 us; speedup vs baseline: 1.0095x; 1.0095x over previous
//
#include <hip/hip_runtime.h>
#include <hip/hip_bf16.h>
#include <stdint.h>
#include <stddef.h>

// NT-Xent loss, B=4096, D=256, N=8192, T=0.5.
// normalize(+zero sumexp) -> fused symmetric ZZ^T GEMM + exp row/col-sum +
// positive capture -> 1-block finalize/mean. No NxN materialization.
//
// R12: ASM-PINNED B PREFETCH. R7-R11 plateau at ~47 us: compiler always
// sinks B loads next to their uses with tight vmcnt waits (R11 VGPR=80
// proves the source-level pipeline was deleted), so every wave exposes full
// L2 latency and the four pipes (MFMA/LDS/TA/VALU, ~33 us serial sum) never
// overlap. Fix is the hipBLASLt/AITER pattern the compiler can't express
// from HIP: loads as asm volatile global_load_dwordx4 into pinned reg quads
// (2 groups x 8, 16 outstanding), consumption gated by asm
// "s_waitcnt vmcnt(8)" that TIES the fragment regs (MFMAs data-ordered
// after the wait; asm-volatile mutual order fixes the FIFO accounting).
// Loop body has ZERO other vmem: colsum atomics deferred via small LDS
// buffer + post-loop drain; pos stores only in the last (tail) iteration.
// Carry-overs: A-tile in LDS staged once (single barrier, XOR-swizzled,
// conflict-free), 64-granular symmetry (R8/R10, HW-verified), exp2f builtin.
// Harness note: ~58-60 us of dur_us is fixed overhead (268 MB ws re-poison
// fill + input restores) outside kernel control.

#define B_ROWS 4096
#define D_DIM  256
#define N_ROWS 8192
#define BM 64

typedef __bf16 bf16;
typedef bf16  bf16x8  __attribute__((ext_vector_type(8)));
typedef bf16  bf16x4  __attribute__((ext_vector_type(4)));
typedef float floatx4 __attribute__((ext_vector_type(4)));
typedef int   intx4   __attribute__((ext_vector_type(4)));

// asm-pinned 16B global load, optional byte-offset literal
#define GLOADO(dst, p, o) \
  asm volatile("global_load_dwordx4 %0, %1, off offset:" o \
               : "=v"(dst) : "v"(p))
// wait until <=8 vmem outstanding; ties a group so consumers order after it
#define WAIT8(g) \
  asm volatile("s_waitcnt vmcnt(8)" \
               : "+v"(g[0]), "+v"(g[1]), "+v"(g[2]), "+v"(g[3]), \
                 "+v"(g[4]), "+v"(g[5]), "+v"(g[6]), "+v"(g[7]))

// ---------------------------------------------------------------- normalize
// One wave per row: 256 fp32 -> L2-normalized bf16. Also zeroes sumexp[row].
__global__ __launch_bounds__(256) void normalize_kernel(
    const float* __restrict__ z_i, const float* __restrict__ z_j,
    bf16* __restrict__ zn, float* __restrict__ sumexp) {
  const int wave = threadIdx.x >> 6;
  const int lane = threadIdx.x & 63;
  const int row  = blockIdx.x * 4 + wave;
  const float* src = (row < B_ROWS) ? (z_i + (size_t)row * D_DIM)
                                    : (z_j + (size_t)(row - B_ROWS) * D_DIM);
  float4 v = ((const float4*)src)[lane];
  float ss = v.x * v.x + v.y * v.y + v.z * v.z + v.w * v.w;
  #pragma unroll
  for (int m = 1; m < 64; m <<= 1) ss += __shfl_xor(ss, m);
  const float rn = rsqrtf(ss);
  bf16x4 o;
  o[0] = (bf16)(v.x * rn);
  o[1] = (bf16)(v.y * rn);
  o[2] = (bf16)(v.z * rn);
  o[3] = (bf16)(v.w * rn);
  ((bf16x4*)(zn + (size_t)row * D_DIM))[lane] = o;
  if (lane == 0) sumexp[row] = 0.f;
}

// ------------------------------------------------------- fused sim+exp+sum
// Grid: 128 ri x 8 cj = 1024 blocks. Block (ri,cj): pairs s=8cj+p, p=0..7,
// two pairs per iteration (4 iters x 128 cols); cj==7,ri<64 also handles
// s=64 (positive tiles) as a 5th iteration on waves 0,1. 4 waves: wave w
// covers 64 rows x 32 cols of pair (w>>1), col slice (w&1)*32. acc[4][2]
// frags of 16x16x32 bf16 MFMA, full-D. A from LDS (XOR-swizzled slot
// (kc&24)|((kc&7)^(n&7)) -> quarter-wave 2-way = conflict-free). B through
// the asm-pinned 2-group register pipeline described in the header.
__global__ __launch_bounds__(256, 3) void simexp_kernel(
    const bf16* __restrict__ zn, float* __restrict__ sumexp,
    float* __restrict__ pos) {
  __shared__ __align__(16) bf16 As[BM * D_DIM];  // 32 KB
  __shared__ float cbuf[4][5][2][16];            // deferred col-sums, 2.5 KB

  const int tid   = threadIdx.x;
  const int wave  = tid >> 6;
  const int lane  = tid & 63;
  const int lcol  = lane & 15;   // MFMA: A/B input row-col index
  const int lquad = lane >> 4;   // MFMA: k-group / C row-group
  const int ri = blockIdx.x >> 3;   // row tile 0..127 (64-row granularity)
  const int cj = blockIdx.x & 7;    // s-chunk 0..7
  const int row_base = ri * BM;
  const bool tail_block = (cj == 7 && ri < 64);
  const int my_niter = (tail_block && wave < 2) ? 5 : 4;

  // stage A-tile once (8 x global_load_lds width-16 per thread)
  {
    const bf16* asrc = zn + (size_t)row_base * D_DIM;
    #pragma unroll
    for (int it = 0; it < 8; ++it) {
      const int s   = it * 256 + tid;   // chunk slot 0..2047
      const int n   = s >> 5;           // row-in-tile 0..63
      const int kcs = s & 31;           // swizzled slot
      const int kc  = (kcs & 24) | ((kcs & 7) ^ (n & 7));
      __builtin_amdgcn_global_load_lds(
          (const __attribute__((address_space(1))) unsigned int*)
              (asrc + (size_t)n * D_DIM + kc * 8),
          (__attribute__((address_space(3))) unsigned int*)&As[s * 8],
          16, 0, 0);
    }
  }

  float rowsum[4][4];  // [ti][r]; row-in-tile = ti*16 + lquad*4 + r
  #pragma unroll
  for (int ti = 0; ti < 4; ++ti)
    #pragma unroll
    for (int r = 0; r < 4; ++r) rowsum[ti][r] = 0.f;

  // per-lane B element offsets within a 64-col tile (constant across iters)
  const int slice_col = (wave & 1) * 32;
  const int boff0 = (slice_col + lcol) * D_DIM + lquad * 8;        // tj=0
  const int boff1 = (slice_col + 16 + lcol) * D_DIM + lquad * 8;   // tj=1

  // ---- preamble: issue both B groups for q=0 (16 outstanding)
  intx4 g0[8], g1[8];
  {
    const int ct0 = (ri + 8 * cj + (wave >> 1)) & 127;
    const bf16* bb = zn + (size_t)ct0 * BM * D_DIM;
    const bf16* p0 = bb + boff0;
    const bf16* p1 = bb + boff1;
    GLOADO(g0[0], p0, "0");   GLOADO(g0[1], p1, "0");
    GLOADO(g0[2], p0, "64");  GLOADO(g0[3], p1, "64");
    GLOADO(g0[4], p0, "128"); GLOADO(g0[5], p1, "128");
    GLOADO(g0[6], p0, "192"); GLOADO(g0[7], p1, "192");
    GLOADO(g1[0], p0, "256"); GLOADO(g1[1], p1, "256");
    GLOADO(g1[2], p0, "320"); GLOADO(g1[3], p1, "320");
    GLOADO(g1[4], p0, "384"); GLOADO(g1[5], p1, "384");
    GLOADO(g1[6], p0, "448"); GLOADO(g1[7], p1, "448");
  }

  __syncthreads();  // A staged & visible (drains vmcnt; accounting still ok)

  #pragma unroll 1
  for (int q = 0; q < my_niter; ++q) {
    const bool tail = (q == 4);
    const int ct = tail ? (ri + 64)
                        : ((ri + 8 * cj + 2 * q + (wave >> 1)) & 127);

    floatx4 acc[4][2];
    #pragma unroll
    for (int ti = 0; ti < 4; ++ti)
      #pragma unroll
      for (int tj = 0; tj < 2; ++tj) acc[ti][tj] = floatx4{0.f, 0.f, 0.f, 0.f};

    // next-iteration base pointers (clamped on last iter: harmless re-fetch)
    const int nq  = (q + 1 < my_niter) ? q + 1 : q;
    const int nct = (nq == 4) ? (ri + 64)
                              : ((ri + 8 * cj + 2 * nq + (wave >> 1)) & 127);
    const bf16* nb  = zn + (size_t)nct * BM * D_DIM;
    const bf16* np0 = nb + boff0;
    const bf16* np1 = nb + boff1;

    // ---- half 1: wait g0 (8 newest = g1 stay in flight), consume kq 0..3
    WAIT8(g0);
    #pragma unroll
    for (int kq = 0; kq < 4; ++kq) {
      const int kc   = kq * 4 + lquad;
      const int slot = (kc & 24) | ((kc & 7) ^ (lcol & 7));
      #pragma unroll
      for (int ti = 0; ti < 4; ++ti) {
        const bf16x8 a =
            *(const bf16x8*)&As[(ti * 16 + lcol) * D_DIM + slot * 8];
        acc[ti][0] = __builtin_amdgcn_mfma_f32_16x16x32_bf16(
            a, __builtin_bit_cast(bf16x8, g0[2 * kq]), acc[ti][0], 0, 0, 0);
        acc[ti][1] = __builtin_amdgcn_mfma_f32_16x16x32_bf16(
            a, __builtin_bit_cast(bf16x8, g0[2 * kq + 1]), acc[ti][1],
            0, 0, 0);
      }
    }
    // refill g0 with next iteration's kq 0..3
    GLOADO(g0[0], np0, "0");   GLOADO(g0[1], np1, "0");
    GLOADO(g0[2], np0, "64");  GLOADO(g0[3], np1, "64");
    GLOADO(g0[4], np0, "128"); GLOADO(g0[5], np1, "128");
    GLOADO(g0[6], np0, "192"); GLOADO(g0[7], np1, "192");

    // ---- half 2: wait g1 (8 newest = refilled g0), consume kq 4..7
    WAIT8(g1);
    #pragma unroll
    for (int kq = 4; kq < 8; ++kq) {
      const int kc   = kq * 4 + lquad;
      const int slot = (kc & 24) | ((kc & 7) ^ (lcol & 7));
      #pragma unroll
      for (int ti = 0; ti < 4; ++ti) {
        const bf16x8 a =
            *(const bf16x8*)&As[(ti * 16 + lcol) * D_DIM + slot * 8];
        acc[ti][0] = __builtin_amdgcn_mfma_f32_16x16x32_bf16(
            a, __builtin_bit_cast(bf16x8, g1[2 * (kq - 4)]), acc[ti][0],
            0, 0, 0);
        acc[ti][1] = __builtin_amdgcn_mfma_f32_16x16x32_bf16(
            a, __builtin_bit_cast(bf16x8, g1[2 * (kq - 4) + 1]), acc[ti][1],
            0, 0, 0);
      }
    }
    // refill g1 with next iteration's kq 4..7
    GLOADO(g1[0], np0, "256"); GLOADO(g1[1], np1, "256");
    GLOADO(g1[2], np0, "320"); GLOADO(g1[3], np1, "320");
    GLOADO(g1[4], np0, "384"); GLOADO(g1[5], np1, "384");
    GLOADO(g1[6], np0, "448"); GLOADO(g1[7], np1, "448");

    // ---- epilogue: e = exp(sim/T) = 2^(v * 2/ln2); NO vmem except the
    // tail-iteration pos stores (last iter -> no later manual waits).
    const bool diagw = (cj == 0 && q == 0 && wave < 2);  // ct == ri tile
    const int col_base = ct * BM + slice_col;
    float colsum[2] = {0.f, 0.f};
    #pragma unroll
    for (int ti = 0; ti < 4; ++ti) {
      #pragma unroll
      for (int tj = 0; tj < 2; ++tj) {
        #pragma unroll
        for (int r = 0; r < 4; ++r) {
          const float v = acc[ti][tj][r];
          float e = __builtin_amdgcn_exp2f(v * 2.8853900817779268f);
          if (diagw || tail) {
            const int rg = row_base + ti * 16 + lquad * 4 + r;
            const int cg = col_base + tj * 16 + lcol;
            if (diagw && cg == rg) e = 0.f;              // mask self
            if (tail && cg == rg + B_ROWS) {             // positive pair
              pos[rg] = 2.0f * v;
              pos[cg] = 2.0f * v;
            }
          }
          rowsum[ti][r] += e;
          colsum[tj]    += e;
        }
      }
    }
    // reduce col-sums across quads now (LDS-pipe shuffles, no vmem),
    // park in LDS for the post-loop atomic drain.
    float cs0 = colsum[0];
    cs0 += __shfl_xor(cs0, 16);
    cs0 += __shfl_xor(cs0, 32);
    float cs1 = colsum[1];
    cs1 += __shfl_xor(cs1, 16);
    cs1 += __shfl_xor(cs1, 32);
    if (lane < 16) {
      cbuf[wave][q][0][lane] = cs0;
      cbuf[wave][q][1][lane] = cs1;
    }
  }

  asm volatile("s_waitcnt vmcnt(0)" ::: "memory");  // drain pinned loads
  __syncthreads();  // all waves' cbuf entries visible

  // drain deferred col-sums: one atomic per (wave,q,tj,lcol) entry
  {
    const int totq = tail_block ? 5 : 4;
    for (int idx = tid; idx < totq * 128; idx += 256) {
      const int lc = idx & 15;
      const int tj = (idx >> 4) & 1;
      const int w  = (idx >> 5) & 3;
      const int q  = idx >> 7;
      if (q == 4 && w >= 2) continue;               // tail only on waves 0,1
      if (q == 0 && cj == 0 && w < 2) continue;     // diag: no col half
      const int ct = (q == 4) ? (ri + 64)
                              : ((ri + 8 * cj + 2 * q + (w >> 1)) & 127);
      const int col = ct * BM + (w & 1) * 32 + tj * 16 + lc;
      atomicAdd(&sumexp[col], cbuf[w][q][tj][lc]);
    }
  }

  // reduce the 16 col-lanes of rowsum, then 1 atomic per row per wave
  #pragma unroll
  for (int ti = 0; ti < 4; ++ti) {
    #pragma unroll
    for (int r = 0; r < 4; ++r) {
      float s2 = rowsum[ti][r];
      s2 += __shfl_xor(s2, 1);
      s2 += __shfl_xor(s2, 2);
      s2 += __shfl_xor(s2, 4);
      s2 += __shfl_xor(s2, 8);
      if (lcol == 0) {
        const int grow = row_base + ti * 16 + lquad * 4 + r;
        atomicAdd(&sumexp[grow], s2);
      }
    }
  }
}

// ------------------------------------------------- finalize + mean (1 block)
// loss_i = log(sumexp_i) - pos_i ; out = mean(loss)
__global__ __launch_bounds__(1024) void reduce_kernel(
    const float* __restrict__ sumexp, const float* __restrict__ pos,
    float* __restrict__ out) {
  __shared__ float ws[16];
  const int tid = threadIdx.x;
  float s = 0.f;
  const float ln2 = 0.6931471805599453f;
  for (int k = tid; k < N_ROWS; k += 1024)
    s += __builtin_amdgcn_logf(sumexp[k]) * ln2 - pos[k];
  #pragma unroll
  for (int m = 1; m < 64; m <<= 1) s += __shfl_xor(s, m);
  const int wave = tid >> 6, lane = tid & 63;
  if (lane == 0) ws[wave] = s;
  __syncthreads();
  if (wave == 0) {
    float t = (lane < 16) ? ws[lane] : 0.f;
    #pragma unroll
    for (int m = 1; m < 16; m <<= 1) t += __shfl_xor(t, m);
    if (lane == 0) out[0] = t * (1.0f / N_ROWS);
  }
}

extern "C" void kernel_launch(void* const* d_in, const int* in_sizes, int n_in,
                              void* d_out, int out_size, void* d_ws,
                              size_t ws_size, hipStream_t stream) {
  const float* z_i = (const float*)d_in[0];
  const float* z_j = (const float*)d_in[1];
  float* out = (float*)d_out;

  // workspace layout: zn (4 MB bf16) | sumexp (32 KB) | pos (32 KB)
  bf16* zn = (bf16*)d_ws;
  float* sumexp = (float*)((char*)d_ws + (size_t)N_ROWS * D_DIM * sizeof(bf16));
  float* pos = sumexp + N_ROWS;

  normalize_kernel<<<N_ROWS / 4, 256, 0, stream>>>(z_i, z_j, zn, sumexp);
  simexp_kernel<<<1024, 256, 0, stream>>>(zn, sumexp, pos);
  reduce_kernel<<<1, 1024, 0, stream>>>(sumexp, pos, out);
}

// Round 13
// 104.684 us; speedup vs baseline: 1.0484x; 1.0386x over previous
//
#include <hip/hip_runtime.h>
#include <hip/hip_bf16.h>
#include <stdint.h>
#include <stddef.h>

// NT-Xent loss, B=4096, D=256, N=8192, T=0.5.
// normalize(+zero sumexp) -> fused symmetric ZZ^T GEMM + exp row/col-sum +
// positive capture -> 1-block finalize/mean. No NxN materialization.
//
// R13 = R8 (empirical best kernel: ~42 us simexp; BM=128 pair-symmetric,
// B full-depth LDS double-buffered via global_load_lds, one barrier per
// 64-col tile, XOR-swizzled conflict-free staging, exp via v_exp_f32)
// + R12's deferred col-sum epilogue: the per-iteration cross-quad shuffle
// chains (~250 cyc serial DS latency) and global atomics are moved out of
// the barriered K-loop into a 5 KB LDS buffer drained once post-loop.
// In R8 those atomics' vmem entered the FIFO drained by the next barrier's
// vmcnt(0) -> critical-path serialization every iteration.
// Rejected-by-measurement alternatives (R9-R12): no-LDS direct-B (51 us),
// BM=64 A-LDS (47), register pipelines incl. asm-pinned vmcnt(8) (47-49).
// The global_load_lds + 128-tile structure empirically beats them all.
// Harness note: ~57 us of dur_us is fixed (268 MB ws re-poison fill ~44 us
// + restores + small kernels) outside kernel control.

#define B_ROWS 4096
#define D_DIM  256
#define N_ROWS 8192
#define BM 128
#define BN 64

typedef __bf16 bf16;
typedef bf16  bf16x8  __attribute__((ext_vector_type(8)));
typedef bf16  bf16x4  __attribute__((ext_vector_type(4)));
typedef float floatx4 __attribute__((ext_vector_type(4)));

// ---------------------------------------------------------------- normalize
// One wave per row: 256 fp32 -> L2-normalized bf16. Also zeroes sumexp[row].
__global__ __launch_bounds__(256) void normalize_kernel(
    const float* __restrict__ z_i, const float* __restrict__ z_j,
    bf16* __restrict__ zn, float* __restrict__ sumexp) {
  const int wave = threadIdx.x >> 6;
  const int lane = threadIdx.x & 63;
  const int row  = blockIdx.x * 4 + wave;
  const float* src = (row < B_ROWS) ? (z_i + (size_t)row * D_DIM)
                                    : (z_j + (size_t)(row - B_ROWS) * D_DIM);
  float4 v = ((const float4*)src)[lane];
  float ss = v.x * v.x + v.y * v.y + v.z * v.z + v.w * v.w;
  #pragma unroll
  for (int m = 1; m < 64; m <<= 1) ss += __shfl_xor(ss, m);
  const float rn = rsqrtf(ss);
  bf16x4 o;
  o[0] = (bf16)(v.x * rn);
  o[1] = (bf16)(v.y * rn);
  o[2] = (bf16)(v.z * rn);
  o[3] = (bf16)(v.w * rn);
  ((bf16x4*)(zn + (size_t)row * D_DIM))[lane] = o;
  if (lane == 0) sumexp[row] = 0.f;
}

// ------------------------------------------------------- fused sim+exp+sum
// Grid: 64 ri x 8 cj = 512 blocks (2/CU). Block (ri,cj) handles tile-pairs
// s = 4cj+p, p=0..3 (+p=4 i.e. s=32 when cj==7 && ri<32); each pair = two
// 64-col sub-tiles -> 8 or 10 iterations. 4 waves in 2x2; wave = 64 rows x
// 32 cols = 4x2 frags of 16x16x32 bf16 MFMA, full-D accumulate.
// LDS B layout XOR-swizzled (conflict-free, verified R2/R3): 16B chunk of
// row n, k-chunk kc lives at slot n*32 + ((kc&24)|((kc&7)^(n&7))); swizzle
// applied on the GLOBAL source address. Read-side key: lcol&7.
__global__ __launch_bounds__(256, 2) void simexp_kernel(
    const bf16* __restrict__ zn, float* __restrict__ sumexp,
    float* __restrict__ pos) {
  __shared__ __align__(16) bf16 Bs[2][BN * D_DIM];  // 2 x 32 KB
  __shared__ float cbuf[4][10][2][16];              // deferred col-sums, 5 KB

  const int tid   = threadIdx.x;
  const int wave  = tid >> 6;
  const int lane  = tid & 63;
  const int lcol  = lane & 15;   // MFMA: A row / B col / C col
  const int lquad = lane >> 4;   // MFMA: k-group / C row-group
  const int wr = (wave >> 1) * 64;  // wave row offset in 128
  const int wc = (wave & 1) * 32;   // wave col offset in 64
  const int ri = blockIdx.x >> 3;   // row tile 0..63
  const int cj = blockIdx.x & 7;    // s-chunk 0..7
  const int row_base = ri * BM;
  const int niter = (cj == 7 && ri < 32) ? 10 : 8;

  // j64-tile index for iteration it: pair p = it>>1, ct = (ri+4cj+p) & 63
  auto jt64 = [&](int it) {
    return 2 * ((ri + 4 * cj + (it >> 1)) & 63) + (it & 1);
  };

  // stage B j64-tile jt into buffer buf (8 global_load_lds x 16 B / thread)
  auto stageB = [&](int buf, int jt) {
    const bf16* src = zn + (size_t)jt * BN * D_DIM;
    #pragma unroll
    for (int it = 0; it < 8; ++it) {
      const int s   = it * 256 + tid;   // chunk slot 0..2047
      const int n   = s >> 5;           // row 0..63
      const int kcs = s & 31;           // swizzled k-chunk slot
      const int kc  = (kcs & 24) | ((kcs & 7) ^ (n & 7));
      __builtin_amdgcn_global_load_lds(
          (const __attribute__((address_space(1))) unsigned int*)
              (src + (size_t)n * D_DIM + kc * 8),
          (__attribute__((address_space(3))) unsigned int*)&Bs[buf][s * 8],
          16, 0, 0);
    }
  };

  stageB(0, jt64(0));  // first prefetch in flight while A loads below

  // A fragments, register-resident (or L1-remat, as the allocator decides —
  // this was the measured-best configuration, R8).
  // af[ti][kq]: row = row_base+wr+ti*16+lcol, k = kq*32 + lquad*8 .. +7
  floatx4 af[4][8];
  #pragma unroll
  for (int ti = 0; ti < 4; ++ti) {
    const bf16* arow =
        zn + (size_t)(row_base + wr + ti * 16 + lcol) * D_DIM + lquad * 8;
    #pragma unroll
    for (int kq = 0; kq < 8; ++kq)
      af[ti][kq] = *(const floatx4*)(arow + kq * 32);
  }

  float rowsum[4][4];  // [ti][r]; row = wr + ti*16 + lquad*4 + r
  #pragma unroll
  for (int ti = 0; ti < 4; ++ti)
    #pragma unroll
    for (int r = 0; r < 4; ++r) rowsum[ti][r] = 0.f;

  #pragma unroll 1  // keep body small (I$); niter is dynamic anyway
  for (int t = 0; t < niter; ++t) {
    __syncthreads();  // drains prefetch for buf[t&1]; fences other-buf reads
    if (t + 1 < niter) stageB((t + 1) & 1, jt64(t + 1));

    floatx4 acc[4][2];
    #pragma unroll
    for (int ti = 0; ti < 4; ++ti)
      #pragma unroll
      for (int tj = 0; tj < 2; ++tj) acc[ti][tj] = floatx4{0.f, 0.f, 0.f, 0.f};

    const bf16* bbase = &Bs[t & 1][0];
    #pragma unroll
    for (int kq = 0; kq < 8; ++kq) {
      const int kc  = kq * 4 + lquad;
      const int kcs = (kc & 24) | ((kc & 7) ^ (lcol & 7));
      bf16x8 bfr[2];
      #pragma unroll
      for (int tj = 0; tj < 2; ++tj) {
        const int n = wc + tj * 16 + lcol;
        bfr[tj] = *(const bf16x8*)(bbase + n * D_DIM + kcs * 8);
      }
      #pragma unroll
      for (int ti = 0; ti < 4; ++ti)
        #pragma unroll
        for (int tj = 0; tj < 2; ++tj)
          acc[ti][tj] = __builtin_amdgcn_mfma_f32_16x16x32_bf16(
              __builtin_bit_cast(bf16x8, af[ti][kq]), bfr[tj], acc[ti][tj],
              0, 0, 0);
    }

    // epilogue: e = exp(sim/T) = exp(2*dot) = 2^(v * 2/ln2)
    const int s    = 4 * cj + (t >> 1);
    const bool diag = (s == 0);
    const bool posT = (s == 32);
    const int jt = jt64(t);
    const int col_base = jt * BN;
    float colsum[2] = {0.f, 0.f};
    #pragma unroll
    for (int ti = 0; ti < 4; ++ti) {
      #pragma unroll
      for (int tj = 0; tj < 2; ++tj) {
        #pragma unroll
        for (int r = 0; r < 4; ++r) {
          const float v = acc[ti][tj][r];
          float e = __builtin_amdgcn_exp2f(v * 2.8853900817779268f);
          if (diag || posT) {
            const int rg = row_base + wr + ti * 16 + lquad * 4 + r;
            const int cg = col_base + wc + tj * 16 + lcol;
            if (diag && cg == rg) e = 0.f;               // mask self
            if (posT && cg == rg + B_ROWS) {             // positive pair
              pos[rg] = 2.0f * v;
              pos[cg] = 2.0f * v;
            }
          }
          rowsum[ti][r] += e;
          colsum[tj]    += e;
        }
      }
    }

    // quad-reduce col-sums, park in LDS; atomic drain happens post-loop
    // (keeps global atomics + their vmcnt out of the barriered loop).
    float cs0 = colsum[0];
    cs0 += __shfl_xor(cs0, 16);
    cs0 += __shfl_xor(cs0, 32);
    float cs1 = colsum[1];
    cs1 += __shfl_xor(cs1, 16);
    cs1 += __shfl_xor(cs1, 32);
    if (lane < 16) {
      cbuf[wave][t][0][lane] = cs0;
      cbuf[wave][t][1][lane] = cs1;
    }
  }

  __syncthreads();  // all waves' cbuf entries visible

  // drain deferred col-sums: one atomic per (wave,t,tj,lcol) entry.
  // Skip diag iterations (cj==0, t<2): self-tile row-sums already cover
  // both orientations there.
  for (int idx = tid; idx < niter * 128; idx += 256) {
    const int lc = idx & 15;
    const int tj = (idx >> 4) & 1;
    const int w  = (idx >> 5) & 3;
    const int t  = idx >> 7;
    if (cj == 0 && t < 2) continue;
    const int jt  = 2 * ((ri + 4 * cj + (t >> 1)) & 63) + (t & 1);
    const int col = jt * BN + (w & 1) * 32 + tj * 16 + lc;
    atomicAdd(&sumexp[col], cbuf[w][t][tj][lc]);
  }

  // reduce the 16 col-lanes of rowsum, then 1 atomic per row per wave
  #pragma unroll
  for (int ti = 0; ti < 4; ++ti) {
    #pragma unroll
    for (int r = 0; r < 4; ++r) {
      float s2 = rowsum[ti][r];
      s2 += __shfl_xor(s2, 1);
      s2 += __shfl_xor(s2, 2);
      s2 += __shfl_xor(s2, 4);
      s2 += __shfl_xor(s2, 8);
      if (lcol == 0) {
        const int grow = row_base + wr + ti * 16 + lquad * 4 + r;
        atomicAdd(&sumexp[grow], s2);
      }
    }
  }
}

// ------------------------------------------------- finalize + mean (1 block)
// loss_i = log(sumexp_i) - pos_i ; out = mean(loss)
__global__ __launch_bounds__(1024) void reduce_kernel(
    const float* __restrict__ sumexp, const float* __restrict__ pos,
    float* __restrict__ out) {
  __shared__ float ws[16];
  const int tid = threadIdx.x;
  float s = 0.f;
  const float ln2 = 0.6931471805599453f;
  for (int k = tid; k < N_ROWS; k += 1024)
    s += __builtin_amdgcn_logf(sumexp[k]) * ln2 - pos[k];
  #pragma unroll
  for (int m = 1; m < 64; m <<= 1) s += __shfl_xor(s, m);
  const int wave = tid >> 6, lane = tid & 63;
  if (lane == 0) ws[wave] = s;
  __syncthreads();
  if (wave == 0) {
    float t = (lane < 16) ? ws[lane] : 0.f;
    #pragma unroll
    for (int m = 1; m < 16; m <<= 1) t += __shfl_xor(t, m);
    if (lane == 0) out[0] = t * (1.0f / N_ROWS);
  }
}

extern "C" void kernel_launch(void* const* d_in, const int* in_sizes, int n_in,
                              void* d_out, int out_size, void* d_ws,
                              size_t ws_size, hipStream_t stream) {
  const float* z_i = (const float*)d_in[0];
  const float* z_j = (const float*)d_in[1];
  float* out = (float*)d_out;

  // workspace layout: zn (4 MB bf16) | sumexp (32 KB) | pos (32 KB)
  bf16* zn = (bf16*)d_ws;
  float* sumexp = (float*)((char*)d_ws + (size_t)N_ROWS * D_DIM * sizeof(bf16));
  float* pos = sumexp + N_ROWS;

  normalize_kernel<<<N_ROWS / 4, 256, 0, stream>>>(z_i, z_j, zn, sumexp);
  simexp_kernel<<<512, 256, 0, stream>>>(zn, sumexp, pos);
  reduce_kernel<<<1, 1024, 0, stream>>>(sumexp, pos, out);
}